// Round 11
// baseline (261.884 us; speedup 1.0000x reference)
//
#include <hip/hip_runtime.h>

#define IMG_H 512
#define IMG_W 512
#define NCH 3
#define NB 32
#define RSTRIP 16
#define NSTRIP (IMG_H / RSTRIP)   // 32 strips per channel-image

typedef unsigned int u32;

// Async-stage one 512-float row half-pair into LDS: 2 x global_load_lds of
// 16B/lane (64 lanes x 16B = 1024B each). lds_base is wave-uniform; HW writes
// lane i at lds_base + i*16. gsrc_lane = row_ptr + lane*4 floats (per-lane).
__device__ __forceinline__ void gld_row(const float* gsrc_lane, float* lds_base) {
    __builtin_amdgcn_global_load_lds(
        (const __attribute__((address_space(1))) u32*)gsrc_lane,
        (__attribute__((address_space(3))) u32*)lds_base, 16, 0, 0);
    __builtin_amdgcn_global_load_lds(
        (const __attribute__((address_space(1))) u32*)(gsrc_lane + 256),
        (__attribute__((address_space(3))) u32*)(lds_base + 256), 16, 0, 0);
}

// One wave (64-thread block) owns a 512-wide strip of RSTRIP output rows; lane
// owns 8 cols. Vertical 7-tap window = 5 running column-sums; entering row
// (cold, HBM) arrives via global_load_lds ring (4 slots, depth-2 prefetch,
// counted vmcnt waits, never 0); leaving row re-loaded to regs (L1/L2-warm).
// Horizontal 7-tap via lane shfl of vertical sums. No barriers (1 wave/block).
// NOTE: keep VGPR <= 128 if possible (waves/SIMD halves above 128 - R9), and
// NEVER add a min-waves launch_bounds arg (R4: 64-VGPR cap -> 1.4GB spills).
__global__ __launch_bounds__(64) void ssim_kernel(const float* __restrict__ x,
                                                  const float* __restrict__ y,
                                                  float* __restrict__ out)
{
    __shared__ float ring[4][2][512];   // [slot][x/y][col] = 16 KB

    const int lane = threadIdx.x;
    const int wid  = blockIdx.x;
    const int b     = wid / (NCH * NSTRIP);
    const int rem   = wid % (NCH * NSTRIP);
    const int ch    = rem / NSTRIP;
    const int strip = rem % NSTRIP;
    const int r0    = strip * RSTRIP;

    const int imgbase = (b * NCH + ch) * (IMG_H * IMG_W);   // int-safe
    const float* __restrict__ xq = x + imgbase;             // row-addressed
    const float* __restrict__ yq = y + imgbase;
    const int lane8 = lane * 8;
    const float* __restrict__ xp = xq + lane8;              // lane-addressed
    const float* __restrict__ yp = yq + lane8;

    float vsx[8], vsy[8], vsxx[8], vsyy[8], vsxy[8];
    #pragma unroll
    for (int i = 0; i < 8; ++i) { vsx[i]=vsy[i]=vsxx[i]=vsyy[i]=vsxy[i]=0.f; }

    // ---- prologue: accumulate rows r0-3 .. r0+3 (zero-padded above) ----
    #pragma unroll
    for (int j = -3; j <= 3; ++j) {
        const int rr = r0 + j;                 // <= 499, only rr<0 possible OOB
        if (rr >= 0) {
            const int ro = rr * IMG_W;
            float xn[8], yn[8];
            *(float4*)&xn[0] = *(const float4*)(xp + ro);
            *(float4*)&xn[4] = *(const float4*)(xp + ro + 4);
            *(float4*)&yn[0] = *(const float4*)(yp + ro);
            *(float4*)&yn[4] = *(const float4*)(yp + ro + 4);
            #pragma unroll
            for (int i = 0; i < 8; ++i) {
                vsx[i] += xn[i];
                vsy[i] += yn[i];
                vsxx[i] = fmaf(xn[i], xn[i], vsxx[i]);
                vsyy[i] = fmaf(yn[i], yn[i], vsyy[i]);
                vsxy[i] = fmaf(xn[i], yn[i], vsxy[i]);
            }
        }
    }

    // ---- prefill DMA ring: bundles 0,1 (entering rows r0+4, r0+5) ----
    #pragma unroll
    for (int pb = 0; pb < 2; ++pb) {
        const int ra = r0 + pb + 4;            // <= 501, always in range
        gld_row(xq + ra * IMG_W + lane * 4, &ring[pb][0][0]);
        gld_row(yq + ra * IMG_W + lane * 4, &ring[pb][1][0]);
    }

    const float C1v = 1e-4f;
    const float C2v = 9e-4f;
    const float inv49 = 1.0f / 49.0f;
    float acc = 0.f;

// shuffles + horizontal sliding 7-tap + SSIM for one output row (no slide)
#define SSIM_ROW()                                                          \
    {                                                                       \
        float hlx[3], hly[3], hlxx[3], hlyy[3], hlxy[3];                    \
        float hrx[3], hry[3], hrxx[3], hryy[3], hrxy[3];                    \
        _Pragma("unroll")                                                   \
        for (int k = 0; k < 3; ++k) {                                       \
            float t;                                                        \
            t = __shfl_up(vsx[5+k], 1, 64);  hlx[k]  = (lane == 0)  ? 0.f : t; \
            t = __shfl_up(vsy[5+k], 1, 64);  hly[k]  = (lane == 0)  ? 0.f : t; \
            t = __shfl_up(vsxx[5+k], 1, 64); hlxx[k] = (lane == 0)  ? 0.f : t; \
            t = __shfl_up(vsyy[5+k], 1, 64); hlyy[k] = (lane == 0)  ? 0.f : t; \
            t = __shfl_up(vsxy[5+k], 1, 64); hlxy[k] = (lane == 0)  ? 0.f : t; \
            t = __shfl_down(vsx[k], 1, 64);  hrx[k]  = (lane == 63) ? 0.f : t; \
            t = __shfl_down(vsy[k], 1, 64);  hry[k]  = (lane == 63) ? 0.f : t; \
            t = __shfl_down(vsxx[k], 1, 64); hrxx[k] = (lane == 63) ? 0.f : t; \
            t = __shfl_down(vsyy[k], 1, 64); hryy[k] = (lane == 63) ? 0.f : t; \
            t = __shfl_down(vsxy[k], 1, 64); hrxy[k] = (lane == 63) ? 0.f : t; \
        }                                                                   \
        float hx  = hlx[0]+hlx[1]+hlx[2]+vsx[0]+vsx[1]+vsx[2]+vsx[3];       \
        float hy  = hly[0]+hly[1]+hly[2]+vsy[0]+vsy[1]+vsy[2]+vsy[3];       \
        float hxx = hlxx[0]+hlxx[1]+hlxx[2]+vsxx[0]+vsxx[1]+vsxx[2]+vsxx[3];\
        float hyy = hlyy[0]+hlyy[1]+hlyy[2]+vsyy[0]+vsyy[1]+vsyy[2]+vsyy[3];\
        float hxy = hlxy[0]+hlxy[1]+hlxy[2]+vsxy[0]+vsxy[1]+vsxy[2]+vsxy[3];\
        _Pragma("unroll")                                                   \
        for (int i = 0; i < 8; ++i) {                                       \
            if (i > 0) {                                                    \
                const float ax  = (i+6 < 11) ? vsx[i+3]  : hrx[i-5];        \
                const float ay  = (i+6 < 11) ? vsy[i+3]  : hry[i-5];        \
                const float axx = (i+6 < 11) ? vsxx[i+3] : hrxx[i-5];       \
                const float ayy = (i+6 < 11) ? vsyy[i+3] : hryy[i-5];       \
                const float axy = (i+6 < 11) ? vsxy[i+3] : hrxy[i-5];       \
                const float sx_ = (i-1 < 3) ? hlx[i-1]  : vsx[i-4];         \
                const float sy_ = (i-1 < 3) ? hly[i-1]  : vsy[i-4];         \
                const float sxx_= (i-1 < 3) ? hlxx[i-1] : vsxx[i-4];        \
                const float syy_= (i-1 < 3) ? hlyy[i-1] : vsyy[i-4];        \
                const float sxy_= (i-1 < 3) ? hlxy[i-1] : vsxy[i-4];        \
                hx += ax - sx_;  hy += ay - sy_;                            \
                hxx += axx - sxx_; hyy += ayy - syy_; hxy += axy - sxy_;    \
            }                                                               \
            const float mx = hx * inv49, my = hy * inv49;                   \
            const float sxx = fmaf(-mx, mx, hxx * inv49);                   \
            const float syy = fmaf(-my, my, hyy * inv49);                   \
            const float sxy = fmaf(-mx, my, hxy * inv49);                   \
            const float num = fmaf(2.f * mx, my, C1v) * fmaf(2.f, sxy, C2v);\
            const float den = fmaf(mx, mx, fmaf(my, my, C1v)) * (sxx + syy + C2v); \
            acc += num * __builtin_amdgcn_rcpf(den + 1e-12f);               \
        }                                                                   \
    }

    #pragma unroll 1
    for (int u = 0; u < RSTRIP - 1; ++u) {
        // (1) leaving-row register loads — ALWAYS 4 VMEM (clamped, zeroed later)
        const int rsU = r0 + u - 3;
        const int roS = (rsU < 0 ? 0 : rsU) * IMG_W;
        float xo[8], yo[8], xa[8], ya[8];
        *(float4*)&xo[0] = *(const float4*)(xp + roS);
        *(float4*)&xo[4] = *(const float4*)(xp + roS + 4);
        *(float4*)&yo[0] = *(const float4*)(yp + roS);
        *(float4*)&yo[4] = *(const float4*)(yp + roS + 4);

        // (2) issue DMA bundle u+2 — ALWAYS 4 gld_lds (clamped row)
        {
            const int rab = r0 + u + 6;
            const int roA = (rab > IMG_H - 1 ? IMG_H - 1 : rab) * IMG_W;
            float* sl2 = &ring[(u + 2) & 3][0][0];
            gld_row(xq + roA + lane * 4, sl2);
            gld_row(yq + roA + lane * 4, sl2 + 512);
        }

        // (3) wait for bundle u: 12 newer VMEM ops allowed to stay in flight
        asm volatile("s_waitcnt vmcnt(12)" ::: "memory");

        // (4) read entering rows from ring slot u
        {
            const float* sl0 = &ring[u & 3][0][0];
            *(float4*)&xa[0] = *(const float4*)(sl0 + lane8);
            *(float4*)&xa[4] = *(const float4*)(sl0 + lane8 + 4);
            *(float4*)&ya[0] = *(const float4*)(sl0 + 512 + lane8);
            *(float4*)&ya[4] = *(const float4*)(sl0 + 512 + lane8 + 4);
        }
        const int raU = r0 + u + 4;
        if (raU >= IMG_H) {
            #pragma unroll
            for (int i = 0; i < 8; ++i) { xa[i] = 0.f; ya[i] = 0.f; }
        }
        if (rsU < 0) {
            #pragma unroll
            for (int i = 0; i < 8; ++i) { xo[i] = 0.f; yo[i] = 0.f; }
        }

        // (5) SSIM for output row r0+u from current window
        SSIM_ROW();

        // (6) slide the vertical window: +row(raU), -row(rsU)
        #pragma unroll
        for (int i = 0; i < 8; ++i) {
            const float dx = xa[i] - xo[i], sx = xa[i] + xo[i];
            const float dy = ya[i] - yo[i], sy = ya[i] + yo[i];
            vsx[i] += dx;
            vsy[i] += dy;
            vsxx[i] = fmaf(dx, sx, vsxx[i]);
            vsyy[i] = fmaf(dy, sy, vsyy[i]);
            vsxy[i] = fmaf(xa[i], ya[i], vsxy[i] - xo[i] * yo[i]);
        }
    }

    // tail output row (u = RSTRIP-1): window already in place
    SSIM_ROW();
#undef SSIM_ROW

    // wave reduction + one atomic per wave
    #pragma unroll
    for (int off = 32; off; off >>= 1) acc += __shfl_down(acc, off, 64);
    if (lane == 0)
        atomicAdd(&out[b], acc * (1.0f / ((float)NCH * IMG_H * IMG_W)));
}

extern "C" void kernel_launch(void* const* d_in, const int* in_sizes, int n_in,
                              void* d_out, int out_size, void* d_ws, size_t ws_size,
                              hipStream_t stream) {
    const float* x = (const float*)d_in[0];
    const float* y = (const float*)d_in[1];
    float* out = (float*)d_out;
    hipMemsetAsync(out, 0, sizeof(float) * NB, stream);
    const int nblocks = NB * NCH * NSTRIP;      // 3072 blocks x 64 threads
    ssim_kernel<<<nblocks, 64, 0, stream>>>(x, y, out);
}